// Round 7
// baseline (1365.184 us; speedup 1.0000x reference)
//
#include <hip/hip_runtime.h>
#include <hip/hip_bf16.h>
#include <cstdint>

#define DIM 128
#define BK_SHIFT 6
#define BK_NODES 64           // nodes per bucket (64 => 32KB f32 acc tile in LDS)
#define MAX_BUCKETS 2048      // supports N <= 131072
#define CUR_STRIDE 16         // pad bucket cursors: 1 per 64B line
#define ST 16384              // edges per scatter block
#define EPT 16                // edges per thread (ST/1024)
#define CAPB 1536             // slack slots per bucket (mean 1024, +16 sigma)
#define PERSIST_BLOCKS 512    // 2 blocks/CU persistent for the fused kernel

typedef float f32x4  __attribute__((ext_vector_type(4)));
typedef short bf16x8 __attribute__((ext_vector_type(8)));   // 8 bf16 in 4 VGPRs

__device__ __forceinline__ unsigned bf16_rne(float f) {
    unsigned u = __float_as_uint(f);
    return (u + 0x7fffu + ((u >> 16) & 1u)) >> 16;   // round-to-nearest-even
}

// ---------------- dispatch A: zero bcursor + deg + gctr ----------------
__global__ __launch_bounds__(1024) void zero_kernel(int* __restrict__ bcursor,
                                                    int* __restrict__ deg,
                                                    int* __restrict__ gctr,
                                                    int nbcur, int N) {
    int t = blockIdx.x * 1024 + threadIdx.x;
    if (t < nbcur) bcursor[t] = 0;
    if (t < N) deg[t] = 0;
    if (t == 0) *gctr = 0;
}

// ---------------- dispatch B: scatter (+deg count)  ||  y = bf16(x)  ||  Wt = bf16(W^T) ----------------
// Blocks 0..scb-1: block-aggregated bucket scatter (LDS hist -> one global
// reservation atomic per (block,bucket) -> contiguous-run stores) + per-edge
// deg[dst] atomicAdd (replaces build_csr's histogram).
// Blocks scb..scb+yb-1: streaming f32->bf16 conversion of x (pure BW work
// that overlaps the scatter blocks' atomic/latency stalls).
// Last blocks: Wt transpose-convert.
__global__ __launch_bounds__(1024) void prep_kernel(const int* __restrict__ src,
                                                    const int* __restrict__ dst,
                                                    int* __restrict__ bcursor,
                                                    int* __restrict__ bbuf,
                                                    int* __restrict__ deg,
                                                    const float* __restrict__ x,
                                                    ushort* __restrict__ y,
                                                    const float* __restrict__ W,
                                                    ushort* __restrict__ Wt,
                                                    int E, int nbk, int N,
                                                    int scb, int yb) {
    int b = blockIdx.x, tid = threadIdx.x;
    if (b < scb) {
        __shared__ int h[MAX_BUCKETS];   // count, then relative base
        for (int i = tid; i < nbk; i += 1024) h[i] = 0;
        __syncthreads();
        int base = b * ST;
        int bk[EPT], rk[EPT], pk[EPT];
        #pragma unroll
        for (int k = 0; k < EPT; ++k) {
            int e = base + k * 1024 + tid;
            bk[k] = -1;
            if (e < E) {
                int d = dst[e];
                int bu = ((unsigned)d) >> BK_SHIFT;
                bk[k] = bu;
                pk[k] = (src[e] << BK_SHIFT) | (d & (BK_NODES - 1));
                rk[k] = atomicAdd(&h[bu], 1);
                atomicAdd(&deg[d], 1);           // in-degree (dinv derived later)
            }
        }
        __syncthreads();
        for (int i = tid; i < nbk; i += 1024) {
            int c = h[i];
            h[i] = c ? atomicAdd(&bcursor[i * CUR_STRIDE], c) : 0;   // relative base
        }
        __syncthreads();
        #pragma unroll
        for (int k = 0; k < EPT; ++k) {
            if (bk[k] >= 0) {
                int pos = h[bk[k]] + rk[k];
                if (pos < CAPB) bbuf[(size_t)bk[k] * CAPB + pos] = pk[k];
            }
        }
    } else if (b < scb + yb) {
        int t = (b - scb) * 1024 + tid;          // one float4 -> 4 bf16 (8B)
        if (t < N * (DIM / 4)) {
            float4 v = ((const float4*)x)[t];
            uint2 o;
            o.x = bf16_rne(v.x) | (bf16_rne(v.y) << 16);
            o.y = bf16_rne(v.z) | (bf16_rne(v.w) << 16);
            ((uint2*)y)[t] = o;
        }
    } else {
        int idx = (b - scb - yb) * 1024 + tid;
        if (idx < DIM * DIM) {
            int k = idx >> 7, c = idx & (DIM - 1);
            Wt[c * DIM + k] = (ushort)bf16_rne(W[idx]);
        }
    }
}

// ---------------- dispatch C: FUSED bucket aggregation + MFMA GEMM + bias + PReLU ----------------
// Persistent 512 blocks grab 64-node buckets from a global counter. Per
// bucket: stage its (unsorted) edge list to LDS, then all 16 waves stream
// edges; per edge all 64 lanes load one dword of the 256B source row
// (lane l = channels 2l,2l+1), scale by rsqrtf(deg[s]+1), and ds_add_f32
// into the bucket's f32 accumulator tile acc[64][128] (order-insensitive =>
// no CSR sort needed; build_csr eliminated). Epilogue: add self-loop term,
// scale by dinv(dst), round to bf16 in-place (reg-staged across a barrier),
// then the proven 16x16x32 MFMA GEMM (B-fragments register-resident) with
// fused bias+PReLU and direct f32 store.
__global__ __launch_bounds__(1024) void agg_gemm_kernel(const ushort* __restrict__ y,
                                                        const int* __restrict__ bbuf,
                                                        const int* __restrict__ bcursor,
                                                        const int* __restrict__ deg,
                                                        const ushort* __restrict__ Wt,
                                                        const float* __restrict__ bias,
                                                        const float* __restrict__ alpha,
                                                        float* __restrict__ out,
                                                        int* __restrict__ gctr,
                                                        int N, int nbk) {
    __shared__ float acc[BK_NODES][DIM];   // 32 KB; reused as bf16 [64][136] post-barrier
    __shared__ int ent[CAPB];              // 6 KB staged bucket entries
    __shared__ int s_tile;
    int tid  = threadIdx.x;
    int lane = tid & 63;
    int wid  = __builtin_amdgcn_readfirstlane((int)(tid >> 6));   // 0..15
    int m = lane & 15, g = lane >> 4;

    // register-resident B fragment for this wave's column tile + epilogue consts
    int ct  = wid & 7;
    int rt0 = wid >> 3;
    bf16x8 bfrag[4];
    #pragma unroll
    for (int ks = 0; ks < 4; ++ks)
        bfrag[ks] = *(const bf16x8*)(Wt + (size_t)(ct * 16 + m) * DIM + ks * 32 + g * 8);
    int col = ct * 16 + m;
    float bb = bias[col], al = alpha[col];

    for (;;) {
        __syncthreads();                   // prev bucket's GEMM done: acc/ent/s_tile free
        if (tid == 0) s_tile = atomicAdd(gctr, 1);
        for (int i = tid; i < BK_NODES * DIM; i += 1024) ((float*)acc)[i] = 0.f;
        __syncthreads();
        int tile = s_tile;
        if (tile >= nbk) break;

        int count = bcursor[tile * CUR_STRIDE];
        if (count > CAPB) count = CAPB;
        int ebase = tile * CAPB;
        for (int i = tid; i < count; i += 1024) ent[i] = bbuf[ebase + i];
        __syncthreads();

        // ---- gather/accumulate: wave-uniform 4-entry chunks ----
        for (int j0 = wid * 4; j0 < count; j0 += 64) {
            int pe[4]; uint vv[4]; int dg[4];
            #pragma unroll
            for (int i = 0; i < 4; ++i)
                pe[i] = (j0 + i < count) ? ent[j0 + i] : -1;
            #pragma unroll
            for (int i = 0; i < 4; ++i) {
                if (pe[i] >= 0) {
                    int s = pe[i] >> BK_SHIFT;
                    vv[i] = ((const uint*)y)[(size_t)s * (DIM / 2) + lane];
                    dg[i] = deg[s];
                }
            }
            #pragma unroll
            for (int i = 0; i < 4; ++i) {
                if (pe[i] >= 0) {
                    float w = rsqrtf((float)(dg[i] + 1));
                    int d = pe[i] & (BK_NODES - 1);
                    atomicAdd(&acc[d][2 * lane],     w * __uint_as_float(vv[i] << 16));
                    atomicAdd(&acc[d][2 * lane + 1], w * __uint_as_float(vv[i] & 0xffff0000u));
                }
            }
        }
        __syncthreads();

        // ---- epilogue: self term + scale + bf16 round, in-place (reg-staged) ----
        int nb = tile * BK_NODES;
        float e0[4], e1[4], dio[4]; uint sv[4];
        #pragma unroll
        for (int i = 0; i < 4; ++i) {
            int r = wid * 4 + i;
            int node = nb + r;
            e0[i] = acc[r][2 * lane];
            e1[i] = acc[r][2 * lane + 1];
            if (node < N) {
                sv[i]  = ((const uint*)y)[(size_t)node * (DIM / 2) + lane];
                dio[i] = rsqrtf((float)(deg[node] + 1));
            } else { sv[i] = 0u; dio[i] = 0.f; }
        }
        __syncthreads();                   // all f32 reads done before bf16 overwrite
        ushort* hb = (ushort*)acc;         // [64][136] rows, 272B stride
        #pragma unroll
        for (int i = 0; i < 4; ++i) {
            int r = wid * 4 + i;
            float di = dio[i];
            float f0 = di * (e0[i] + di * __uint_as_float(sv[i] << 16));
            float f1 = di * (e1[i] + di * __uint_as_float(sv[i] & 0xffff0000u));
            ((uint*)(hb + (size_t)r * 136))[lane] = bf16_rne(f0) | (bf16_rne(f1) << 16);
        }
        __syncthreads();

        // ---- GEMM: 2 row-tiles per wave, zero global loads ----
        #pragma unroll
        for (int tt = 0; tt < 2; ++tt) {
            int rt = rt0 + tt * 2;
            f32x4 a4 = (f32x4){0.f, 0.f, 0.f, 0.f};
            #pragma unroll
            for (int ks = 0; ks < 4; ++ks) {
                bf16x8 av = *(const bf16x8*)(hb + (size_t)(rt * 16 + m) * 136 + ks * 32 + g * 8);
                a4 = __builtin_amdgcn_mfma_f32_16x16x32_bf16(av, bfrag[ks], a4, 0, 0, 0);
            }
            int rowbase = nb + rt * 16;
            #pragma unroll
            for (int reg = 0; reg < 4; ++reg) {
                int grow = rowbase + g * 4 + reg;
                if (grow < N) {
                    float vv = a4[reg] + bb;
                    vv = vv > 0.f ? vv : al * vv;
                    out[(size_t)grow * DIM + col] = vv;
                }
            }
        }
    }
}

extern "C" void kernel_launch(void* const* d_in, const int* in_sizes, int n_in,
                              void* d_out, int out_size, void* d_ws, size_t ws_size,
                              hipStream_t stream) {
    const float* x     = (const float*)d_in[0];
    const int*   ei    = (const int*)d_in[1];
    const float* W     = (const float*)d_in[2];
    const float* bias  = (const float*)d_in[3];
    const float* alpha = (const float*)d_in[4];
    float* out = (float*)d_out;

    int N = in_sizes[0] / DIM;
    int E = in_sizes[1] / 2;
    const int* src = ei;
    const int* dst = ei + E;
    int nbk = (N + BK_NODES - 1) >> BK_SHIFT;   // 1563 buckets of 64 nodes

    char* ws = (char*)d_ws;
    size_t off = 0;
    auto alloc = [&](size_t bytes) -> char* {
        char* p = ws + off;
        off += (bytes + 255) & ~(size_t)255;
        return p;
    };
    int*    bbuf    = (int*)alloc((size_t)nbk * CAPB * 4);   // 9.6 MB
    ushort* y       = (ushort*)alloc((size_t)N * DIM * 2);   // 25.6 MB
    int*    bcursor = (int*)alloc((size_t)nbk * CUR_STRIDE * 4);  // 100 KB
    int*    deg     = (int*)alloc((size_t)N * 4);            // 400 KB
    ushort* Wt      = (ushort*)alloc((size_t)DIM * DIM * 2); // 32 KB
    int*    gctr    = (int*)alloc(256);
    // total ~36 MB (< 64.87 MB proven available)

    int nbcur = nbk * CUR_STRIDE;
    int zg  = ((nbcur > N ? nbcur : N) + 1023) / 1024;
    int scb = (E + ST - 1) / ST;                 // 98 scatter blocks
    int yb  = (N * (DIM / 4) + 1023) / 1024;     // 3125 y-convert blocks
    int wtb = (DIM * DIM + 1023) / 1024;         // 16 Wt blocks

    zero_kernel<<<zg, 1024, 0, stream>>>(bcursor, deg, gctr, nbcur, N);
    prep_kernel<<<scb + yb + wtb, 1024, 0, stream>>>(src, dst, bcursor, bbuf, deg,
                                                     x, y, W, Wt, E, nbk, N, scb, yb);
    agg_gemm_kernel<<<PERSIST_BLOCKS, 1024, 0, stream>>>(y, bbuf, bcursor, deg,
                                                         Wt, bias, alpha, out, gctr, N, nbk);
}

// Round 8
// 302.546 us; speedup vs baseline: 4.5123x; 4.5123x over previous
//
#include <hip/hip_runtime.h>
#include <hip/hip_bf16.h>
#include <cstdint>

#define DIM 128
#define BK_SHIFT 6
#define BK_NODES 64           // nodes per bucket/tile
#define MAX_BUCKETS 2048      // supports N <= 131072
#define CUR_STRIDE 16         // pad bucket cursors: 1 per 64B line
#define ST 16384              // edges per scatter block
#define EPT 16                // edges per thread (ST/1024)
#define CAPB 1536             // slack slots per bucket (mean 1024, +16 sigma)
#define PERSIST_BLOCKS 512    // 2 blocks/CU persistent for the fused kernel

typedef float f32x4  __attribute__((ext_vector_type(4)));
typedef short bf16x8 __attribute__((ext_vector_type(8)));   // 8 bf16 in 4 VGPRs

__device__ __forceinline__ unsigned bf16_rne(float f) {
    unsigned u = __float_as_uint(f);
    return (u + 0x7fffu + ((u >> 16) & 1u)) >> 16;   // round-to-nearest-even
}

// ---------------- dispatch A: zero bcursor + deg + gctr ----------------
__global__ __launch_bounds__(1024) void zero_kernel(int* __restrict__ bcursor,
                                                    int* __restrict__ deg,
                                                    int* __restrict__ gctr,
                                                    int nbcur, int N) {
    int t = blockIdx.x * 1024 + threadIdx.x;
    if (t < nbcur) bcursor[t] = 0;
    if (t < N) deg[t] = 0;
    if (t == 0) *gctr = 0;
}

// ---------------- dispatch B: scatter (+deg count)  ||  y = bf16(x)  ||  Wt = bf16(W^T) ----------------
// Identical to the R7 prep (correctness-verified). Scatter blocks run first
// and their atomic/latency stalls hide under the y-convert blocks' BW work.
__global__ __launch_bounds__(1024) void prep_kernel(const int* __restrict__ src,
                                                    const int* __restrict__ dst,
                                                    int* __restrict__ bcursor,
                                                    int* __restrict__ bbuf,
                                                    int* __restrict__ deg,
                                                    const float* __restrict__ x,
                                                    ushort* __restrict__ y,
                                                    const float* __restrict__ W,
                                                    ushort* __restrict__ Wt,
                                                    int E, int nbk, int N,
                                                    int scb, int yb) {
    int b = blockIdx.x, tid = threadIdx.x;
    if (b < scb) {
        __shared__ int h[MAX_BUCKETS];   // count, then relative base
        for (int i = tid; i < nbk; i += 1024) h[i] = 0;
        __syncthreads();
        int base = b * ST;
        int bk[EPT], rk[EPT], pk[EPT];
        #pragma unroll
        for (int k = 0; k < EPT; ++k) {
            int e = base + k * 1024 + tid;
            bk[k] = -1;
            if (e < E) {
                int d = dst[e];
                int bu = ((unsigned)d) >> BK_SHIFT;
                bk[k] = bu;
                pk[k] = (src[e] << BK_SHIFT) | (d & (BK_NODES - 1));
                rk[k] = atomicAdd(&h[bu], 1);
                atomicAdd(&deg[d], 1);           // in-degree (dinv = rsqrt(deg+1))
            }
        }
        __syncthreads();
        for (int i = tid; i < nbk; i += 1024) {
            int c = h[i];
            h[i] = c ? atomicAdd(&bcursor[i * CUR_STRIDE], c) : 0;   // relative base
        }
        __syncthreads();
        #pragma unroll
        for (int k = 0; k < EPT; ++k) {
            if (bk[k] >= 0) {
                int pos = h[bk[k]] + rk[k];
                if (pos < CAPB) bbuf[(size_t)bk[k] * CAPB + pos] = pk[k];
            }
        }
    } else if (b < scb + yb) {
        int t = (b - scb) * 1024 + tid;          // one float4 -> 4 bf16 (8B)
        if (t < N * (DIM / 4)) {
            float4 v = ((const float4*)x)[t];
            uint2 o;
            o.x = bf16_rne(v.x) | (bf16_rne(v.y) << 16);
            o.y = bf16_rne(v.z) | (bf16_rne(v.w) << 16);
            ((uint2*)y)[t] = o;
        }
    } else {
        int idx = (b - scb - yb) * 1024 + tid;
        if (idx < DIM * DIM) {
            int k = idx >> 7, c = idx & (DIM - 1);
            Wt[c * DIM + k] = (ushort)bf16_rne(W[idx]);
        }
    }
}

// ---------------- dispatch C: FUSED sort + aggregation + MFMA GEMM + bias + PReLU ----------------
// Persistent 512 blocks grab 64-node buckets. Per bucket:
//  1) stage entries to LDS + 64-counter histogram (1 int atomic/edge),
//  2) wave-0 shfl prefix scan, placement scatter to ent2 (1 int atomic/edge)
//     -> bucket-local sorted edge lists (build_csr dispatch eliminated),
//  3) R5-PROVEN register gather: dynamic node grab, 16 lanes x uint4 per
//     source row (4 rows in flight/instr), f32 register accumulation,
//     dinv on the fly = rsqrtf(deg+1), shfl_xor(16,32) combine,
//  4) bf16 rows -> LDS tile, then the proven 16x16x32 MFMA GEMM with
//     register-resident B fragments, fused bias+PReLU, direct f32 store.
// NO f32 LDS atomics anywhere (R7 lesson: data path through ds_add = 14x).
__device__ __forceinline__ void agg_accum(float* a, uint4 v, float wt) {
    a[0] += wt * __uint_as_float(v.x << 16);
    a[1] += wt * __uint_as_float(v.x & 0xffff0000u);
    a[2] += wt * __uint_as_float(v.y << 16);
    a[3] += wt * __uint_as_float(v.y & 0xffff0000u);
    a[4] += wt * __uint_as_float(v.z << 16);
    a[5] += wt * __uint_as_float(v.z & 0xffff0000u);
    a[6] += wt * __uint_as_float(v.w << 16);
    a[7] += wt * __uint_as_float(v.w & 0xffff0000u);
}

__global__ __launch_bounds__(1024) void agg_gemm_kernel(const ushort* __restrict__ y,
                                                        const int* __restrict__ bbuf,
                                                        const int* __restrict__ bcursor,
                                                        const int* __restrict__ deg,
                                                        const ushort* __restrict__ Wt,
                                                        const float* __restrict__ bias,
                                                        const float* __restrict__ alpha,
                                                        float* __restrict__ out,
                                                        int* __restrict__ gctr,
                                                        int N, int nbk) {
    __shared__ ushort hT[BK_NODES][136];   // 17.4 KB bf16 rows (272B stride)
    __shared__ int ent[CAPB];              // 6 KB raw entries
    __shared__ int ent2[CAPB];             // 6 KB sorted src ids
    __shared__ int cnt[BK_NODES];
    __shared__ int sc[BK_NODES];
    __shared__ int cur[BK_NODES];
    __shared__ int s_tile, nodectr;
    int tid  = threadIdx.x;
    int lane = tid & 63;
    int wid  = __builtin_amdgcn_readfirstlane((int)(tid >> 6));   // 0..15
    int m = lane & 15, g = lane >> 4;

    // register-resident B fragment for this wave's column tile + epilogue consts
    int ct  = wid & 7;
    int rt0 = wid >> 3;
    bf16x8 bfrag[4];
    #pragma unroll
    for (int ks = 0; ks < 4; ++ks)
        bfrag[ks] = *(const bf16x8*)(Wt + (size_t)(ct * 16 + m) * DIM + ks * 32 + g * 8);
    int col = ct * 16 + m;
    float bb = bias[col], al = alpha[col];

    for (;;) {
        __syncthreads();                   // prev GEMM done: hT/counters reusable
        if (tid == 0) { s_tile = atomicAdd(gctr, 1); nodectr = 0; }
        if (tid < BK_NODES) cnt[tid] = 0;
        __syncthreads();
        int tile = s_tile;
        if (tile >= nbk) break;

        int count = bcursor[tile * CUR_STRIDE];
        if (count > CAPB) count = CAPB;
        int ebase = tile * CAPB;

        // 1) stage + histogram
        for (int i = tid; i < count; i += 1024) {
            int e = bbuf[ebase + i];
            ent[i] = e;
            atomicAdd(&cnt[e & (BK_NODES - 1)], 1);
        }
        __syncthreads();

        // 2) wave-0 inclusive scan over 64 counters, placement cursors
        if (tid < BK_NODES) {
            int v = cnt[tid];
            #pragma unroll
            for (int d = 1; d < BK_NODES; d <<= 1) {
                int u = __shfl_up(v, d);
                if (tid >= d) v += u;
            }
            sc[tid] = v;                   // inclusive scan (stable)
            cur[tid] = v - cnt[tid];       // exclusive base (mutating cursor)
        }
        __syncthreads();
        for (int i = tid; i < count; i += 1024) {
            int e = ent[i];
            int p = atomicAdd(&cur[e & (BK_NODES - 1)], 1);
            ent2[p] = e >> BK_SHIFT;       // sorted source id
        }
        __syncthreads();

        // 3) gather: dynamic node grab, register accumulation (R5 structure)
        int nb = tile * BK_NODES;
        for (;;) {
            int local;
            if (lane == 0) local = atomicAdd(&nodectr, 1);
            local = __builtin_amdgcn_readfirstlane(local);
            if (local >= BK_NODES) break;
            int node = nb + local;

            float a[8];
            #pragma unroll
            for (int c = 0; c < 8; ++c) a[c] = 0.f;
            float di = 0.f;

            if (node < N) {
                int c0  = cnt[local];
                int beg = sc[local] - c0;
                di = rsqrtf((float)(deg[node] + 1));

                {   // self-loop (counted once via group-0 weight)
                    uint4 v = ((const uint4*)(y + (size_t)node * DIM))[m];
                    agg_accum(a, v, (g == 0) ? di : 0.f);
                }

                int t = g;
                int nit = (c0 + 7) >> 3;   // 8 slots (2 packs of 4) per iter
                for (int it = 0; it < nit; ++it, t += 8) {
                    int tB = t + 4;
                    int iA = beg + (t  < c0 ? t  : c0 - 1);
                    int iB = beg + (tB < c0 ? tB : c0 - 1);
                    int sA = ent2[iA];
                    int sB = ent2[iB];
                    float wA = (t  < c0) ? rsqrtf((float)(deg[sA] + 1)) : 0.f;
                    float wB = (tB < c0) ? rsqrtf((float)(deg[sB] + 1)) : 0.f;
                    uint4 vA = ((const uint4*)(y + (size_t)sA * DIM))[m];
                    uint4 vB = ((const uint4*)(y + (size_t)sB * DIM))[m];
                    agg_accum(a, vA, wA);
                    agg_accum(a, vB, wB);
                }

                #pragma unroll
                for (int c = 0; c < 8; ++c) {
                    a[c] += __shfl_xor(a[c], 16);
                    a[c] += __shfl_xor(a[c], 32);
                }
            }

            if (g == 0) {        // bf16 row -> LDS (zeros for node >= N)
                uint4 o;
                o.x = bf16_rne(di * a[0]) | (bf16_rne(di * a[1]) << 16);
                o.y = bf16_rne(di * a[2]) | (bf16_rne(di * a[3]) << 16);
                o.z = bf16_rne(di * a[4]) | (bf16_rne(di * a[5]) << 16);
                o.w = bf16_rne(di * a[6]) | (bf16_rne(di * a[7]) << 16);
                *(uint4*)(&hT[local][m * 8]) = o;
            }
        }
        __syncthreads();

        // 4) GEMM: 2 row-tiles per wave, zero global loads
        #pragma unroll
        for (int tt = 0; tt < 2; ++tt) {
            int rt = rt0 + tt * 2;
            f32x4 a4 = (f32x4){0.f, 0.f, 0.f, 0.f};
            #pragma unroll
            for (int ks = 0; ks < 4; ++ks) {
                bf16x8 av = *(const bf16x8*)(&hT[rt * 16 + m][ks * 32 + g * 8]);
                a4 = __builtin_amdgcn_mfma_f32_16x16x32_bf16(av, bfrag[ks], a4, 0, 0, 0);
            }
            int rowbase = nb + rt * 16;
            #pragma unroll
            for (int reg = 0; reg < 4; ++reg) {
                int grow = rowbase + g * 4 + reg;
                if (grow < N) {
                    float vv = a4[reg] + bb;
                    vv = vv > 0.f ? vv : al * vv;
                    out[(size_t)grow * DIM + col] = vv;
                }
            }
        }
    }
}

extern "C" void kernel_launch(void* const* d_in, const int* in_sizes, int n_in,
                              void* d_out, int out_size, void* d_ws, size_t ws_size,
                              hipStream_t stream) {
    const float* x     = (const float*)d_in[0];
    const int*   ei    = (const int*)d_in[1];
    const float* W     = (const float*)d_in[2];
    const float* bias  = (const float*)d_in[3];
    const float* alpha = (const float*)d_in[4];
    float* out = (float*)d_out;

    int N = in_sizes[0] / DIM;
    int E = in_sizes[1] / 2;
    const int* src = ei;
    const int* dst = ei + E;
    int nbk = (N + BK_NODES - 1) >> BK_SHIFT;   // 1563 buckets of 64 nodes

    char* ws = (char*)d_ws;
    size_t off = 0;
    auto alloc = [&](size_t bytes) -> char* {
        char* p = ws + off;
        off += (bytes + 255) & ~(size_t)255;
        return p;
    };
    int*    bbuf    = (int*)alloc((size_t)nbk * CAPB * 4);   // 9.6 MB
    ushort* y       = (ushort*)alloc((size_t)N * DIM * 2);   // 25.6 MB
    int*    bcursor = (int*)alloc((size_t)nbk * CUR_STRIDE * 4);  // 100 KB
    int*    deg     = (int*)alloc((size_t)N * 4);            // 400 KB
    ushort* Wt      = (ushort*)alloc((size_t)DIM * DIM * 2); // 32 KB
    int*    gctr    = (int*)alloc(256);
    // total ~36 MB (< 64.87 MB proven available)

    int nbcur = nbk * CUR_STRIDE;
    int zg  = ((nbcur > N ? nbcur : N) + 1023) / 1024;
    int scb = (E + ST - 1) / ST;                 // 98 scatter blocks
    int yb  = (N * (DIM / 4) + 1023) / 1024;     // 3125 y-convert blocks
    int wtb = (DIM * DIM + 1023) / 1024;         // 16 Wt blocks

    zero_kernel<<<zg, 1024, 0, stream>>>(bcursor, deg, gctr, nbcur, N);
    prep_kernel<<<scb + yb + wtb, 1024, 0, stream>>>(src, dst, bcursor, bbuf, deg,
                                                     x, y, W, Wt, E, nbk, N, scb, yb);
    agg_gemm_kernel<<<PERSIST_BLOCKS, 1024, 0, stream>>>(y, bbuf, bcursor, deg,
                                                         Wt, bias, alpha, out, gctr, N, nbk);
}

// Round 9
// 216.309 us; speedup vs baseline: 6.3113x; 1.3987x over previous
//
#include <hip/hip_runtime.h>
#include <hip/hip_bf16.h>
#include <cstdint>

#define DIM 128
#define BK_SHIFT 7
#define BK_NODES 128          // nodes per bucket (R5-proven geometry)
#define MAX_BUCKETS 1024      // supports N <= 131072
#define CUR_STRIDE 16         // pad bucket cursors: 1 per 64B line
#define ST 16384              // edges per scatter block
#define EPT 16                // edges per thread (ST/1024)
#define CAP 2560              // slack slots per bucket (mean 2046, >11 sigma)
#define WPB 64                // nodes per fused tile
#define PERSIST_BLOCKS 512    // 2 blocks/CU persistent for the fused kernel

typedef float f32x4  __attribute__((ext_vector_type(4)));
typedef short bf16x8 __attribute__((ext_vector_type(8)));   // 8 bf16 in 4 VGPRs

__device__ __forceinline__ unsigned bf16_rne(float f) {
    unsigned u = __float_as_uint(f);
    return (u + 0x7fffu + ((u >> 16) & 1u)) >> 16;   // round-to-nearest-even
}

// ---------------- dispatch A: zero bcursor + gctr (3 us) ----------------
__global__ __launch_bounds__(1024) void zero_kernel(int* __restrict__ bcursor,
                                                    int* __restrict__ gctr,
                                                    int nbcur) {
    int t = blockIdx.x * 1024 + threadIdx.x;
    if (t < nbcur) bcursor[t] = 0;
    if (t == 0) *gctr = 0;
}

// ---------------- dispatch B: scatter || y = bf16(x) || Wt = bf16(W^T) ----------------
// Blocks 0..scb-1: R5-proven block-aggregated bucket scatter (LDS hist ->
// one global reservation atomic per (block,bucket) -> contiguous-run stores).
// Remaining blocks: streaming f32->bf16 conversion of x and the Wt
// transpose-convert — pure BW work that overlaps the scatter blocks'
// atomic/latency stalls (R8's one sound piece).
__global__ __launch_bounds__(1024) void prep_kernel(const int* __restrict__ src,
                                                    const int* __restrict__ dst,
                                                    int* __restrict__ bcursor,
                                                    int* __restrict__ bbuf,
                                                    const float* __restrict__ x,
                                                    ushort* __restrict__ y,
                                                    const float* __restrict__ W,
                                                    ushort* __restrict__ Wt,
                                                    int E, int nbk, int N,
                                                    int scb, int yb) {
    int b = blockIdx.x, tid = threadIdx.x;
    if (b < scb) {
        __shared__ int h[MAX_BUCKETS];   // count, then relative base
        for (int i = tid; i < nbk; i += 1024) h[i] = 0;
        __syncthreads();
        int base = b * ST;
        int bk[EPT], rk[EPT], pk[EPT];
        #pragma unroll
        for (int k = 0; k < EPT; ++k) {
            int e = base + k * 1024 + tid;
            bk[k] = -1;
            if (e < E) {
                int d = dst[e];
                int bu = ((unsigned)d) >> BK_SHIFT;
                bk[k] = bu;
                pk[k] = (src[e] << BK_SHIFT) | (d & (BK_NODES - 1));
                rk[k] = atomicAdd(&h[bu], 1);
            }
        }
        __syncthreads();
        for (int i = tid; i < nbk; i += 1024) {
            int c = h[i];
            h[i] = c ? atomicAdd(&bcursor[i * CUR_STRIDE], c) : 0;   // relative base
        }
        __syncthreads();
        #pragma unroll
        for (int k = 0; k < EPT; ++k) {
            if (bk[k] >= 0) {
                int pos = h[bk[k]] + rk[k];
                if (pos < CAP) bbuf[(size_t)bk[k] * CAP + pos] = pk[k];
            }
        }
    } else if (b < scb + yb) {
        int t = (b - scb) * 1024 + tid;          // one float4 -> 4 bf16 (8B)
        if (t < N * (DIM / 4)) {
            float4 v = ((const float4*)x)[t];
            uint2 o;
            o.x = bf16_rne(v.x) | (bf16_rne(v.y) << 16);
            o.y = bf16_rne(v.z) | (bf16_rne(v.w) << 16);
            ((uint2*)y)[t] = o;
        }
    } else {
        int idx = (b - scb - yb) * 1024 + tid;
        if (idx < DIM * DIM) {
            int k = idx >> 7, c = idx & (DIM - 1);
            Wt[c * DIM + k] = (ushort)bf16_rne(W[idx]);
        }
    }
}

// ---------------- dispatch C: per-bucket CSR build (R5-proven) ----------------
__global__ __launch_bounds__(256) void build_csr_kernel(const int* __restrict__ bbuf,
                                                        const int* __restrict__ bcursor,
                                                        int* __restrict__ obeg,
                                                        int* __restrict__ oend,
                                                        float* __restrict__ dinv,
                                                        int* __restrict__ csr_src,
                                                        int N) {
    __shared__ int cnt[BK_NODES];
    __shared__ int sc[BK_NODES];
    __shared__ int cur[BK_NODES];
    int b = blockIdx.x, tid = threadIdx.x;
    int count = bcursor[b * CUR_STRIDE];
    if (count > CAP) count = CAP;
    int base = b * CAP;
    if (tid < BK_NODES) cnt[tid] = 0;
    __syncthreads();
    for (int j = tid; j < count; j += 256)
        atomicAdd(&cnt[bbuf[base + j] & (BK_NODES - 1)], 1);
    __syncthreads();
    if (tid < BK_NODES) sc[tid] = cnt[tid];
    __syncthreads();
    for (int d = 1; d < BK_NODES; d <<= 1) {
        int v = (tid >= d && tid < BK_NODES) ? sc[tid - d] : 0;
        __syncthreads();
        if (tid < BK_NODES) sc[tid] += v;
        __syncthreads();
    }
    if (tid < BK_NODES) {
        int node = b * BK_NODES + tid;
        int start = base + sc[tid] - cnt[tid];
        cur[tid] = start;
        if (node < N) {
            obeg[node] = start;
            oend[node] = start + cnt[tid];
            dinv[node] = rsqrtf((float)(cnt[tid] + 1));   // +1 self loop
        }
    }
    __syncthreads();
    for (int j = tid; j < count; j += 256) {
        int p = bbuf[base + j];
        int pos = atomicAdd(&cur[p & (BK_NODES - 1)], 1);
        csr_src[pos] = p >> BK_SHIFT;
    }
}

// ---------------- dispatch D: FUSED agg + GEMM (byte-identical to R5, 85.6us verified) ----------------
__device__ __forceinline__ void agg_accum(float* a, uint4 v, float wt) {
    a[0] += wt * __uint_as_float(v.x << 16);
    a[1] += wt * __uint_as_float(v.x & 0xffff0000u);
    a[2] += wt * __uint_as_float(v.y << 16);
    a[3] += wt * __uint_as_float(v.y & 0xffff0000u);
    a[4] += wt * __uint_as_float(v.z << 16);
    a[5] += wt * __uint_as_float(v.z & 0xffff0000u);
    a[6] += wt * __uint_as_float(v.w << 16);
    a[7] += wt * __uint_as_float(v.w & 0xffff0000u);
}

__global__ __launch_bounds__(1024) void agg_gemm_kernel(const ushort* __restrict__ y,
                                                        const int* __restrict__ csr_src,
                                                        const int* __restrict__ obeg,
                                                        const int* __restrict__ oend,
                                                        const float* __restrict__ dinv,
                                                        const ushort* __restrict__ Wt,
                                                        const float* __restrict__ bias,
                                                        const float* __restrict__ alpha,
                                                        float* __restrict__ out,
                                                        int* __restrict__ gctr,
                                                        int N, int ntiles) {
    __shared__ ushort hT[WPB][136];   // 272B row stride: 16B-aligned, bank-spread
    __shared__ int s_tile, nodectr;
    int tid  = threadIdx.x;
    int lane = tid & 63;
    int wid  = __builtin_amdgcn_readfirstlane((int)(tid >> 6));   // 0..15
    int g = lane >> 4;           // slot group / quad
    int m = lane & 15;           // 16B chunk / row-in-tile

    // preload: B fragment for this wave's column tile + epilogue constants
    int ct  = wid & 7;
    int rt0 = wid >> 3;
    bf16x8 bfrag[4];
    #pragma unroll
    for (int ks = 0; ks < 4; ++ks)
        bfrag[ks] = *(const bf16x8*)(Wt + (size_t)(ct * 16 + m) * DIM + ks * 32 + g * 8);
    int col = ct * 16 + m;
    float bb = bias[col], al = alpha[col];

    for (;;) {
        __syncthreads();                       // prev GEMM done: hT/nodectr free
        if (tid == 0) { s_tile = atomicAdd(gctr, 1); nodectr = 0; }
        __syncthreads();
        int tile = s_tile;
        if (tile >= ntiles) break;
        int nbase = tile * WPB;

        // ---- gather phase: dynamic node grab within tile ----
        for (;;) {
            int local;
            if (lane == 0) local = atomicAdd(&nodectr, 1);
            local = __builtin_amdgcn_readfirstlane(local);
            if (local >= WPB) break;
            int node = nbase + local;

            float a[8];
            #pragma unroll
            for (int c = 0; c < 8; ++c) a[c] = 0.f;
            float di = 0.f;

            if (node < N) {
                int beg = obeg[node];
                int cnt = oend[node] - beg;
                di = dinv[node];

                {   // self-loop (counted once via group-0 weight)
                    uint4 v = ((const uint4*)(y + (size_t)node * DIM))[m];
                    agg_accum(a, v, (g == 0) ? di : 0.f);
                }

                int t = g;
                int nit = (cnt + 7) >> 3;    // 8 slots (2 packs of 4) per iter
                for (int it = 0; it < nit; ++it, t += 8) {
                    int tB = t + 4;
                    int iA = beg + (t  < cnt ? t  : cnt - 1);
                    int iB = beg + (tB < cnt ? tB : cnt - 1);
                    int sA = csr_src[iA];
                    int sB = csr_src[iB];
                    float wA = (t  < cnt) ? dinv[sA] : 0.f;
                    float wB = (tB < cnt) ? dinv[sB] : 0.f;
                    uint4 vA = ((const uint4*)(y + (size_t)sA * DIM))[m];
                    uint4 vB = ((const uint4*)(y + (size_t)sB * DIM))[m];
                    agg_accum(a, vA, wA);
                    agg_accum(a, vB, wB);
                }

                #pragma unroll
                for (int c = 0; c < 8; ++c) {
                    a[c] += __shfl_xor(a[c], 16);
                    a[c] += __shfl_xor(a[c], 32);
                }
            }

            if (g == 0) {        // bf16 row -> LDS (zeros for node >= N)
                uint4 o;
                o.x = bf16_rne(di * a[0]) | (bf16_rne(di * a[1]) << 16);
                o.y = bf16_rne(di * a[2]) | (bf16_rne(di * a[3]) << 16);
                o.z = bf16_rne(di * a[4]) | (bf16_rne(di * a[5]) << 16);
                o.w = bf16_rne(di * a[6]) | (bf16_rne(di * a[7]) << 16);
                *(uint4*)(&hT[local][m * 8]) = o;
            }
        }
        __syncthreads();

        // ---- GEMM phase: 2 tasks/wave, zero global loads ----
        #pragma unroll
        for (int tt = 0; tt < 2; ++tt) {
            int rt = rt0 + tt * 2;
            f32x4 acc = (f32x4){0.f, 0.f, 0.f, 0.f};
            #pragma unroll
            for (int ks = 0; ks < 4; ++ks) {
                bf16x8 av = *(const bf16x8*)(&hT[rt * 16 + m][ks * 32 + g * 8]);
                acc = __builtin_amdgcn_mfma_f32_16x16x32_bf16(av, bfrag[ks], acc, 0, 0, 0);
            }
            int rowbase = nbase + rt * 16;
            #pragma unroll
            for (int reg = 0; reg < 4; ++reg) {
                int grow = rowbase + g * 4 + reg;
                if (grow < N) {
                    float vv = acc[reg] + bb;
                    vv = vv > 0.f ? vv : al * vv;
                    out[(size_t)grow * DIM + col] = vv;
                }
            }
        }
    }
}

extern "C" void kernel_launch(void* const* d_in, const int* in_sizes, int n_in,
                              void* d_out, int out_size, void* d_ws, size_t ws_size,
                              hipStream_t stream) {
    const float* x     = (const float*)d_in[0];
    const int*   ei    = (const int*)d_in[1];
    const float* W     = (const float*)d_in[2];
    const float* bias  = (const float*)d_in[3];
    const float* alpha = (const float*)d_in[4];
    float* out = (float*)d_out;

    int N = in_sizes[0] / DIM;
    int E = in_sizes[1] / 2;
    const int* src = ei;
    const int* dst = ei + E;
    int nbk = (N + BK_NODES - 1) >> BK_SHIFT;   // 782 buckets of 128 nodes
    int ntiles = (N + WPB - 1) / WPB;           // 1563 gemm tiles of 64 nodes

    char* ws = (char*)d_ws;
    size_t off = 0;
    auto alloc = [&](size_t bytes) -> char* {
        char* p = ws + off;
        off += (bytes + 255) & ~(size_t)255;
        return p;
    };
    int*    bbuf    = (int*)alloc((size_t)nbk * CAP * 4);    // 8.0 MB
    int*    csr_src = (int*)alloc((size_t)nbk * CAP * 4);    // 8.0 MB slack layout
    ushort* y       = (ushort*)alloc((size_t)N * DIM * 2);   // 25.6 MB
    int*    bcursor = (int*)alloc(((size_t)nbk * CUR_STRIDE + 16) * 4);  // +gctr line
    int*    obeg    = (int*)alloc((size_t)N * 4);
    int*    oend    = (int*)alloc((size_t)N * 4);
    float*  dinv    = (float*)alloc((size_t)N * 4);
    ushort* Wt      = (ushort*)alloc((size_t)DIM * DIM * 2);
    int*    gctr    = bcursor + (size_t)nbk * CUR_STRIDE;
    // total ~43 MB (< 64.87 MB proven available)

    int nbcur = nbk * CUR_STRIDE + 16;
    int zg  = (nbcur + 1023) / 1024;
    int scb = (E + ST - 1) / ST;                 // 98 scatter blocks
    int yb  = (N * (DIM / 4) + 1023) / 1024;     // 3125 y-convert blocks
    int wtb = (DIM * DIM + 1023) / 1024;         // 16 Wt blocks

    zero_kernel<<<zg, 1024, 0, stream>>>(bcursor, gctr, nbcur);
    prep_kernel<<<scb + yb + wtb, 1024, 0, stream>>>(src, dst, bcursor, bbuf,
                                                     x, y, W, Wt, E, nbk, N, scb, yb);
    build_csr_kernel<<<nbk, 256, 0, stream>>>(bbuf, bcursor, obeg, oend, dinv, csr_src, N);
    agg_gemm_kernel<<<PERSIST_BLOCKS, 1024, 0, stream>>>(y, csr_src, obeg, oend, dinv,
                                                         Wt, bias, alpha, out, gctr, N, ntiles);
}